// Round 1
// baseline (499.691 us; speedup 1.0000x reference)
//
#include <hip/hip_runtime.h>

#define N_NODE 10000
#define N_INST 50000
#define N_SVC  20000
#define NEDGE  200000
#define D      128
#define NTASK  200000   // total (relation,dst) rows
#define NEDGE_TOT (6*NEDGE)

typedef unsigned short ushort_t;
typedef __attribute__((ext_vector_type(8))) short short8;
typedef __attribute__((ext_vector_type(4))) float f32x4;

__device__ __forceinline__ ushort_t f2bf(float f) {
  unsigned u = __float_as_uint(f);
  u += 0x7fffu + ((u >> 16) & 1u);   // round-to-nearest-even
  return (ushort_t)(u >> 16);
}

// relation ids: 0:sc(svc->svc) 1:in(inst->node) 2:ni(node->inst) 3:ii(inst->inst) 4:si(svc->inst) 5:is(inst->svc)
// task = global (relation,dst) row id; od index = global (relation,src) id
__device__ __forceinline__ int task_base(int r) {
  const int tb[6] = {0, 20000, 30000, 80000, 130000, 180000};
  return tb[r];
}
__device__ __forceinline__ int od_base(int r) {
  const int ob[6] = {0, 20000, 70000, 80000, 130000, 150000};
  return ob[r];
}

// ---------------- zero workspace counters ----------------
__global__ __launch_bounds__(256) void k_zero(int4* p, int n4) {
  int i = blockIdx.x * blockDim.x + threadIdx.x;
  if (i < n4) p[i] = make_int4(0, 0, 0, 0);
}

// ---------------- convert features + W to bf16 (W transposed & group-concat) ----------------
struct ConvArgs {
  const float* f0; const float* f1; const float* f2;       // node, inst, svc
  ushort_t* xb0; ushort_t* xb1; ushort_t* xb2;
  const float* W[6];
  ushort_t* Wt_node; ushort_t* Wt_inst; ushort_t* Wt_svc;  // [n][k_cat] row-major
};
__global__ __launch_bounds__(256) void k_convert(ConvArgs a) {
  int tid = blockIdx.x * blockDim.x + threadIdx.x;
  const int F0 = N_NODE * D / 4, F1 = N_INST * D / 4, F2 = N_SVC * D / 4;
  const int NF = F0 + F1 + F2;
  if (tid < NF) {
    const float* src; ushort_t* dst; int i;
    if (tid < F0)            { src = a.f0; dst = a.xb0; i = tid; }
    else if (tid < F0 + F1)  { src = a.f1; dst = a.xb1; i = tid - F0; }
    else                     { src = a.f2; dst = a.xb2; i = tid - F0 - F1; }
    float4 v = ((const float4*)src)[i];
    unsigned o0 = (unsigned)f2bf(v.x) | ((unsigned)f2bf(v.y) << 16);
    unsigned o1 = (unsigned)f2bf(v.z) | ((unsigned)f2bf(v.w) << 16);
    ((uint2*)dst)[i] = make_uint2(o0, o1);
  } else {
    int wi = tid - NF;
    if (wi < 6 * D * D) {
      int r = wi / (D * D), idx = wi % (D * D);
      int k = idx / D, n = idx % D;
      float v = a.W[r][k * D + n];
      ushort_t* t; int stride, coff;
      switch (r) {
        case 0: t = a.Wt_svc;  stride = 256; coff = 0;   break; // sc
        case 1: t = a.Wt_node; stride = 128; coff = 0;   break; // in
        case 2: t = a.Wt_inst; stride = 384; coff = 0;   break; // ni
        case 3: t = a.Wt_inst; stride = 384; coff = 128; break; // ii
        case 4: t = a.Wt_inst; stride = 384; coff = 256; break; // si
        default:t = a.Wt_svc;  stride = 256; coff = 128; break; // is
      }
      t[n * stride + coff + k] = f2bf(v);
    }
  }
}

// ---------------- degree count ----------------
struct EdgeArgs {
  const int* src[6]; const int* dst[6];
  int* out_deg; int* in_deg; int* fill; int* row_start; int* slots; int* cursor;
};
__global__ __launch_bounds__(256) void k_count(EdgeArgs a) {
  int tid = blockIdx.x * blockDim.x + threadIdx.x;
  if (tid >= NEDGE_TOT) return;
  int r = tid / NEDGE, e = tid - r * NEDGE;
  atomicAdd(&a.out_deg[od_base(r) + a.src[r][e]], 1);
  atomicAdd(&a.in_deg[task_base(r) + a.dst[r][e]], 1);
}

// ---------------- row slot allocation (wave prefix-scan + one atomic per wave) ----------------
__global__ __launch_bounds__(256) void k_alloc(const int* in_deg, int* row_start, int* cursor) {
  int tid = blockIdx.x * blockDim.x + threadIdx.x;
  int lane = threadIdx.x & 63;
  int deg = (tid < NTASK) ? in_deg[tid] : 0;
  int x = deg;
  #pragma unroll
  for (int d = 1; d < 64; d <<= 1) {
    int y = __shfl_up(x, d, 64);
    if (lane >= d) x += y;
  }
  int base = 0;
  if (lane == 63) base = atomicAdd(cursor, x);   // x@lane63 = wave total
  base = __shfl(base, 63, 64);
  if (tid < NTASK) row_start[tid] = base + x - deg;  // exclusive prefix
}

// ---------------- CSR fill ----------------
__global__ __launch_bounds__(256) void k_fill(EdgeArgs a) {
  int tid = blockIdx.x * blockDim.x + threadIdx.x;
  if (tid >= NEDGE_TOT) return;
  int r = tid / NEDGE, e = tid - r * NEDGE;
  int task = task_base(r) + a.dst[r][e];
  int pos = atomicAdd(&a.fill[task], 1);
  a.slots[a.row_start[task] + pos] = a.src[r][e];
}

// ---------------- aggregation: one wave per (relation,dst) row ----------------
struct AggArgs {
  const ushort_t* xb[3];  // 0 node, 1 inst, 2 svc (bf16, [n][128])
  const int* out_deg; const int* in_deg; const int* row_start; const int* slots;
  ushort_t* agg_node; ushort_t* agg_inst; ushort_t* agg_svc;
};
__global__ __launch_bounds__(256) void k_aggregate(AggArgs a) {
  int wid = (blockIdx.x * blockDim.x + threadIdx.x) >> 6;
  int lane = threadIdx.x & 63;
  int nw = (gridDim.x * blockDim.x) >> 6;
  for (int t = wid; t < NTASK; t += nw) {
    int rel, dst;
    if (t < 20000)       { rel = 0; dst = t; }
    else if (t < 30000)  { rel = 1; dst = t - 20000; }
    else if (t < 80000)  { rel = 2; dst = t - 30000; }
    else if (t < 130000) { rel = 3; dst = t - 80000; }
    else if (t < 180000) { rel = 4; dst = t - 130000; }
    else                 { rel = 5; dst = t - 180000; }
    const int sspace[6] = {2, 1, 0, 1, 2, 1};
    const ushort_t* xb = a.xb[sspace[rel]];
    const int* odp = a.out_deg + od_base(rel);
    int deg = a.in_deg[t];
    int base = a.row_start[t];
    float acc0 = 0.f, acc1 = 0.f;
    int s_cur = 0, od_cur = 1;
    if (deg > 0) { s_cur = a.slots[base]; od_cur = odp[s_cur]; }
    for (int i = 0; i < deg; ++i) {
      int s = s_cur, odv = od_cur;
      if (i + 1 < deg) { s_cur = a.slots[base + i + 1]; od_cur = odp[s_cur]; }  // prefetch next
      float scale = rsqrtf((float)(odv < 1 ? 1 : odv));
      unsigned v = ((const unsigned*)(xb + (size_t)s * D))[lane];
      acc0 = fmaf(__uint_as_float(v << 16), scale, acc0);
      acc1 = fmaf(__uint_as_float(v & 0xffff0000u), scale, acc1);
    }
    float si = rsqrtf((float)(deg < 1 ? 1 : deg));
    ushort_t* out; int stride, coff;
    switch (rel) {
      case 0: out = a.agg_svc;  stride = 256; coff = 0;   break;
      case 1: out = a.agg_node; stride = 128; coff = 0;   break;
      case 2: out = a.agg_inst; stride = 384; coff = 0;   break;
      case 3: out = a.agg_inst; stride = 384; coff = 128; break;
      case 4: out = a.agg_inst; stride = 384; coff = 256; break;
      default:out = a.agg_svc;  stride = 256; coff = 128; break;
    }
    unsigned o = ((unsigned)f2bf(acc1 * si) << 16) | (unsigned)f2bf(acc0 * si);
    ((unsigned*)(out + (size_t)dst * stride + coff))[lane] = o;
  }
}

// ---------------- fused GEMM + bias + mean + relu ----------------
struct GemmGroup {
  const ushort_t* A; const ushort_t* Wt;
  const float* b0; const float* b1; const float* b2;
  float inv_m; int M; int Kg; int out_base; int tile_begin;
};
struct GemmArgs { GemmGroup g[3]; float* out; };

__global__ __launch_bounds__(256) void k_gemm(GemmArgs ga) {
  int bid = blockIdx.x;
  int gi = (bid >= ga.g[2].tile_begin) ? 2 : (bid >= ga.g[1].tile_begin ? 1 : 0);
  GemmGroup g = ga.g[gi];
  int tile = bid - g.tile_begin;

  __shared__ __align__(16) ushort_t As[128 * 48];  // rows padded 32->48 (96B, 16B aligned)
  __shared__ __align__(16) ushort_t Bs[128 * 48];
  __shared__ float bsum[128];

  if (threadIdx.x < 128) {
    float b = g.b0[threadIdx.x];
    if (g.b1) b += g.b1[threadIdx.x];
    if (g.b2) b += g.b2[threadIdx.x];
    bsum[threadIdx.x] = b;
  }

  int wave = threadIdx.x >> 6, lane = threadIdx.x & 63;
  int wm = (wave >> 1) * 64, wn = (wave & 1) * 64;
  int m16 = lane & 15, kq = lane >> 4;
  int row0 = tile * 128;

  f32x4 acc[4][4] = {};

  for (int kc = 0; kc < g.Kg; kc += 32) {
    __syncthreads();
    for (int id = threadIdx.x; id < 1024; id += 256) {
      int half = id >> 9;           // 0:A  1:B
      int cid = id & 511;
      int c = cid & 3, row = cid >> 2;
      if (half == 0) {
        int gr = row0 + row; if (gr >= g.M) gr = g.M - 1;
        uint4 v = *(const uint4*)(g.A + (size_t)gr * g.Kg + kc + c * 8);
        *(uint4*)(&As[row * 48 + c * 8]) = v;
      } else {
        uint4 v = *(const uint4*)(g.Wt + (size_t)row * g.Kg + kc + c * 8);
        *(uint4*)(&Bs[row * 48 + c * 8]) = v;
      }
    }
    __syncthreads();
    short8 av[4], bv[4];
    #pragma unroll
    for (int i = 0; i < 4; i++) av[i] = *(const short8*)(&As[(wm + i * 16 + m16) * 48 + kq * 8]);
    #pragma unroll
    for (int j = 0; j < 4; j++) bv[j] = *(const short8*)(&Bs[(wn + j * 16 + m16) * 48 + kq * 8]);
    #pragma unroll
    for (int i = 0; i < 4; i++)
      #pragma unroll
      for (int j = 0; j < 4; j++)
        acc[i][j] = __builtin_amdgcn_mfma_f32_16x16x32_bf16(av[i], bv[j], acc[i][j], 0, 0, 0);
  }

  // epilogue: D[row=(lane>>4)*4+r][col=lane&15] per 16x16 tile
  #pragma unroll
  for (int i = 0; i < 4; i++) {
    #pragma unroll
    for (int j = 0; j < 4; j++) {
      int col = wn + j * 16 + m16;
      #pragma unroll
      for (int r = 0; r < 4; r++) {
        int row = wm + i * 16 + kq * 4 + r;
        int gr = row0 + row;
        if (gr < g.M) {
          float v = (acc[i][j][r] + bsum[col]) * g.inv_m;
          v = v > 0.f ? v : 0.f;
          ga.out[(size_t)(g.out_base + gr) * D + col] = v;
        }
      }
    }
  }
}

// ---------------- host ----------------
extern "C" void kernel_launch(void* const* d_in, const int* in_sizes, int n_in,
                              void* d_out, int out_size, void* d_ws, size_t ws_size,
                              hipStream_t stream) {
  const float* node_feat = (const float*)d_in[0];
  const float* inst_feat = (const float*)d_in[1];
  const float* svc_feat  = (const float*)d_in[2];
  const int* e_src[6]; const int* e_dst[6]; const float* W[6]; const float* B[6];
  for (int r = 0; r < 6; r++) {
    e_src[r] = (const int*)d_in[3 + 4 * r];
    e_dst[r] = (const int*)d_in[4 + 4 * r];
    W[r]     = (const float*)d_in[5 + 4 * r];
    B[r]     = (const float*)d_in[6 + 4 * r];
  }

  char* ws = (char*)d_ws;
  size_t off = 0;
  auto alloc = [&](size_t bytes) { char* p = ws + off; off += (bytes + 255) & ~(size_t)255; return p; };
  ushort_t* xb_node  = (ushort_t*)alloc((size_t)N_NODE * D * 2);
  ushort_t* xb_inst  = (ushort_t*)alloc((size_t)N_INST * D * 2);
  ushort_t* xb_svc   = (ushort_t*)alloc((size_t)N_SVC  * D * 2);
  ushort_t* Wt_node  = (ushort_t*)alloc(128 * 128 * 2);
  ushort_t* Wt_inst  = (ushort_t*)alloc(128 * 384 * 2);
  ushort_t* Wt_svc   = (ushort_t*)alloc(128 * 256 * 2);
  ushort_t* agg_node = (ushort_t*)alloc((size_t)N_NODE * 128 * 2);
  ushort_t* agg_inst = (ushort_t*)alloc((size_t)N_INST * 384 * 2);
  ushort_t* agg_svc  = (ushort_t*)alloc((size_t)N_SVC  * 256 * 2);
  int* in_deg    = (int*)alloc(NTASK * 4);
  int* out_deg   = (int*)alloc(NTASK * 4);
  int* fill      = (int*)alloc(NTASK * 4);
  int* cursor    = (int*)alloc(256);
  int* row_start = (int*)alloc(NTASK * 4);
  int* slots     = (int*)alloc((size_t)NEDGE_TOT * 4);

  // 1. zero [in_deg .. cursor] block (contiguous by construction above)
  {
    size_t zero_bytes = (char*)row_start - (char*)in_deg;
    int n4 = (int)(zero_bytes / 16);
    k_zero<<<(n4 + 255) / 256, 256, 0, stream>>>((int4*)in_deg, n4);
  }
  // 2. convert features + W
  {
    ConvArgs a;
    a.f0 = node_feat; a.f1 = inst_feat; a.f2 = svc_feat;
    a.xb0 = xb_node; a.xb1 = xb_inst; a.xb2 = xb_svc;
    for (int r = 0; r < 6; r++) a.W[r] = W[r];
    a.Wt_node = Wt_node; a.Wt_inst = Wt_inst; a.Wt_svc = Wt_svc;
    int nthreads = (N_NODE + N_INST + N_SVC) * D / 4 + 6 * D * D;
    k_convert<<<(nthreads + 255) / 256, 256, 0, stream>>>(a);
  }
  EdgeArgs ea;
  for (int r = 0; r < 6; r++) { ea.src[r] = e_src[r]; ea.dst[r] = e_dst[r]; }
  ea.out_deg = out_deg; ea.in_deg = in_deg; ea.fill = fill;
  ea.row_start = row_start; ea.slots = slots; ea.cursor = cursor;
  // 3. count degrees
  k_count<<<(NEDGE_TOT + 255) / 256, 256, 0, stream>>>(ea);
  // 4. allocate row regions
  k_alloc<<<(NTASK + 255) / 256, 256, 0, stream>>>(in_deg, row_start, cursor);
  // 5. fill CSR
  k_fill<<<(NEDGE_TOT + 255) / 256, 256, 0, stream>>>(ea);
  // 6. aggregate
  {
    AggArgs a;
    a.xb[0] = xb_node; a.xb[1] = xb_inst; a.xb[2] = xb_svc;
    a.out_deg = out_deg; a.in_deg = in_deg; a.row_start = row_start; a.slots = slots;
    a.agg_node = agg_node; a.agg_inst = agg_inst; a.agg_svc = agg_svc;
    k_aggregate<<<2048, 256, 0, stream>>>(a);
  }
  // 7. fused GEMM
  {
    GemmArgs ga;
    ga.out = (float*)d_out;
    int t_node = (N_NODE + 127) / 128;   // 79
    int t_inst = (N_INST + 127) / 128;   // 391
    int t_svc  = (N_SVC  + 127) / 128;   // 157
    ga.g[0] = { agg_node, Wt_node, B[1], nullptr, nullptr, 1.0f,        N_NODE, 128, 0,               0 };
    ga.g[1] = { agg_inst, Wt_inst, B[2], B[3],    B[4],    1.0f / 3.0f, N_INST, 384, N_NODE,          t_node };
    ga.g[2] = { agg_svc,  Wt_svc,  B[0], B[5],    nullptr, 0.5f,        N_SVC,  256, N_NODE + N_INST, t_node + t_inst };
    k_gemm<<<t_node + t_inst + t_svc, 256, 0, stream>>>(ga);
  }
}